// Round 2
// baseline (610.058 us; speedup 1.0000x reference)
//
#include <hip/hip_runtime.h>

#define D_SZ 768
#define N_SZ 50000
#define L_SZ 28
#define B_SZ 1024
#define NP   50048   // 391 * 128 (padded N)
#define NT   391     // n-tiles of 128

typedef __bf16 bf16x8 __attribute__((ext_vector_type(8)));
typedef float f32x4 __attribute__((ext_vector_type(4)));
typedef unsigned short u16x8 __attribute__((ext_vector_type(8)));

__device__ __forceinline__ unsigned short f2bf(float f) {
  union { float f; unsigned u; } v; v.f = f;
  unsigned r = v.u + 0x7FFFu + ((v.u >> 16) & 1u);
  return (unsigned short)(r >> 16);
}
__device__ __forceinline__ unsigned cvt_pk_bf16(float lo, float hi) {
  unsigned r;
  asm("v_cvt_pk_bf16_f32 %0, %1, %2" : "=v"(r) : "v"(lo), "v"(hi));
  return r;
}

// ---------------------------------------------------------------------------
// W f32 [768][768] -> bf16 copy.
// ---------------------------------------------------------------------------
__global__ void convW(const float* __restrict__ W, unsigned short* __restrict__ Wb)
{
  const int t = blockIdx.x * 256 + threadIdx.x;   // 73728 threads x 8 elems
  const float4 a0 = *(const float4*)(W + (size_t)t * 8);
  const float4 a1 = *(const float4*)(W + (size_t)t * 8 + 4);
  uint4 o;
  o.x = cvt_pk_bf16(a0.x, a0.y);
  o.y = cvt_pk_bf16(a0.z, a0.w);
  o.z = cvt_pk_bf16(a1.x, a1.y);
  o.w = cvt_pk_bf16(a1.z, a1.w);
  *(uint4*)(Wb + (size_t)t * 8) = o;
}

// ---------------------------------------------------------------------------
// X-stationary projection + row-norm: per block, 64 rows of X staged ONCE into
// LDS (bf16, XOR-swizzled); loop 6 column chunks of W (bf16, global_load_lds
// into conflict-free subtiled layout). Writes unnormalized bf16 Y and
// rinv[row] = 1/max(||y_row||, eps) (f32, from f32 accumulators).
// blockIdx.x < 16 -> features; else ex_features tile (blockIdx.x - 16).
// ---------------------------------------------------------------------------
__global__ __launch_bounds__(512, 1)
void proj_fused(const float* __restrict__ Xf, const float* __restrict__ Xe,
                const unsigned short* __restrict__ Wb,
                unsigned short* __restrict__ Yf, unsigned short* __restrict__ Ye,
                float* __restrict__ rinvF, float* __restrict__ rinvE)
{
  __shared__ __align__(16) unsigned short As[64 * 768];     // 98304 B, swizzled
  __shared__ __align__(16) unsigned short Bs[8 * 128 * 8];  // 16384 B, [kg][n][8]
  __shared__ float ssh[64];
  const int tid = threadIdx.x;
  const int w = tid >> 6, lane = tid & 63;
  const int wr = w >> 2, wc = w & 3;            // 2 (M) x 4 (N) waves
  const int fr = lane & 15, fq = lane >> 4;

  const float* X; unsigned short* Y; float* rinv; int m0, Mvalid;
  if (blockIdx.x < 16) { X = Xf; Y = Yf; rinv = rinvF; m0 = blockIdx.x * 64; Mvalid = B_SZ; }
  else { X = Xe; Y = Ye; rinv = rinvE; m0 = (blockIdx.x - 16) * 64; Mvalid = N_SZ; }

  if (tid < 64) ssh[tid] = 0.f;

  // ---- stage As: 64x768 f32 -> bf16, XOR swizzle byte ^= (row&7)<<4 ----
#pragma unroll
  for (int j = 0; j < 12; ++j) {
    const int c = tid + j * 512;        // 16B-chunk id, 0..6143
    const int row = c / 96;             // 96 chunks per row
    const int cb = c % 96;
    float4 a0, a1;
    if (m0 + row < Mvalid) {
      const float* p = X + (size_t)(m0 + row) * D_SZ + cb * 8;
      a0 = *(const float4*)p; a1 = *(const float4*)(p + 4);
    } else { a0 = make_float4(0.f, 0.f, 0.f, 0.f); a1 = a0; }
    uint4 v;
    v.x = cvt_pk_bf16(a0.x, a0.y);
    v.y = cvt_pk_bf16(a0.z, a0.w);
    v.z = cvt_pk_bf16(a1.x, a1.y);
    v.w = cvt_pk_bf16(a1.z, a1.w);
    const unsigned byte = (unsigned)row * 1536u + (((unsigned)cb * 16u) ^ (((unsigned)row & 7u) << 4));
    *(uint4*)((char*)As + byte) = v;
  }

  float ssq[2][4] = {};

  for (int o0 = 0; o0 < 6; ++o0) {
    f32x4 acc[2][2] = {};
    for (int kk = 0; kk < D_SZ; kk += 64) {
      {
        const int kg = tid >> 7, n = tid & 127;
        const unsigned short* g0 = Wb + (size_t)(o0 * 128 + n) * D_SZ + kk + kg * 8;
        __builtin_amdgcn_global_load_lds((const __attribute__((address_space(1))) void*)g0,
                                         (__attribute__((address_space(3))) void*)&Bs[(kg * 128 + n) * 8],
                                         16, 0, 0);
        __builtin_amdgcn_global_load_lds((const __attribute__((address_space(1))) void*)(g0 + 32),
                                         (__attribute__((address_space(3))) void*)&Bs[((kg + 4) * 128 + n) * 8],
                                         16, 0, 0);
      }
      __syncthreads();
      bf16x8 af[2][2], bv[2][2];
#pragma unroll
      for (int s = 0; s < 2; ++s) {
#pragma unroll
        for (int mi = 0; mi < 2; ++mi) {
          const int row = wr * 32 + mi * 16 + fr;
          const unsigned cb = ((unsigned)((kk + s * 32 + fq * 8) * 2)) ^ (((unsigned)row & 7u) << 4);
          af[mi][s] = *(const bf16x8*)((const char*)As + (unsigned)row * 1536u + cb);
        }
#pragma unroll
        for (int ni = 0; ni < 2; ++ni) {
          const int kg = s * 4 + fq;
          bv[ni][s] = *(const bf16x8*)&Bs[(kg * 128 + wc * 32 + ni * 16 + fr) * 8];
        }
      }
#pragma unroll
      for (int s = 0; s < 2; ++s)
#pragma unroll
        for (int mi = 0; mi < 2; ++mi)
#pragma unroll
          for (int ni = 0; ni < 2; ++ni)
            acc[mi][ni] = __builtin_amdgcn_mfma_f32_16x16x32_bf16(af[mi][s], bv[ni][s], acc[mi][ni], 0, 0, 0);
      __syncthreads();
    }
    // chunk epilogue: write unnormalized bf16 Y, accumulate sum-of-squares
#pragma unroll
    for (int mi = 0; mi < 2; ++mi)
#pragma unroll
      for (int ni = 0; ni < 2; ++ni)
#pragma unroll
        for (int r = 0; r < 4; ++r) {
          const int row = m0 + wr * 32 + mi * 16 + fq * 4 + r;
          const int col = o0 * 128 + wc * 32 + ni * 16 + fr;
          const float v = acc[mi][ni][r];
          Y[(size_t)row * D_SZ + col] = f2bf(v);
          ssq[mi][r] += v * v;
        }
  }

  // reduce ssq over the 16 fr lanes (cols) -> per-row partial; sum waves in LDS
#pragma unroll
  for (int mi = 0; mi < 2; ++mi)
#pragma unroll
    for (int r = 0; r < 4; ++r) {
      float v = ssq[mi][r];
      v += __shfl_xor(v, 1); v += __shfl_xor(v, 2);
      v += __shfl_xor(v, 4); v += __shfl_xor(v, 8);
      if (fr == 0) atomicAdd(&ssh[wr * 32 + mi * 16 + fq * 4 + r], v);
    }
  __syncthreads();
  if (tid < 64) rinv[m0 + tid] = 1.0f / fmaxf(sqrtf(ssh[tid]), 1e-12f);
}

// ---------------------------------------------------------------------------
// Build excT bf16 [32][NP]: excT[l][n] = ex_classes[n][l] (zero-padded).
// ---------------------------------------------------------------------------
__global__ void excT_prep(const float* __restrict__ exc, unsigned short* __restrict__ excT)
{
  __shared__ float lds[64][29];
  const int n0 = blockIdx.x * 64;
  const int tid = threadIdx.x;
  for (int i = tid; i < 64 * L_SZ; i += 256) {
    const int n = i / L_SZ, l = i % L_SZ;
    lds[n][l] = (n0 + n < N_SZ) ? exc[(size_t)(n0 + n) * L_SZ + l] : 0.0f;
  }
  __syncthreads();
  for (int i = tid; i < 32 * 64; i += 256) {
    const int l = i >> 6, n = i & 63;
    const float v = (l < L_SZ) ? lds[n][l] : 0.0f;
    excT[(size_t)l * NP + n0 + n] = f2bf(v);
  }
}

// ---------------------------------------------------------------------------
// Per-class exemplar counts: counts[l] = sum_n ex_classes[n][l].
// ---------------------------------------------------------------------------
__global__ void countsk(const float* __restrict__ exc, float* __restrict__ counts)
{
  const int l = blockIdx.x;
  float c = 0.f;
  for (int n = threadIdx.x; n < N_SZ; n += 256) c += exc[(size_t)n * L_SZ + l];
  __shared__ float red[256];
  red[threadIdx.x] = c;
  __syncthreads();
  for (int s = 128; s; s >>= 1) {
    if (threadIdx.x < s) red[threadIdx.x] += red[threadIdx.x + s];
    __syncthreads();
  }
  if (threadIdx.x == 0) counts[l] = red[0];
}

// ---------------------------------------------------------------------------
// Fused s-GEMM: per 128x128 tile, dot = fn @ exfn^T (K=768, unnormalized),
// s = dot * rinvF[b] * rinvE[n], a = s^3 -> swizzled LDS, then
// echo_part += a @ excT^T (K=128) in AGPRs across 8 tiles; atomics.
// ---------------------------------------------------------------------------
__global__ __launch_bounds__(256, 2)
void echo_gemm(const unsigned short* __restrict__ fn,
               const unsigned short* __restrict__ exfn,
               const unsigned short* __restrict__ excT,
               const float* __restrict__ rinvF,
               const float* __restrict__ rinvE,
               float* __restrict__ echo)
{
  __shared__ __align__(16) unsigned short As[128 * 32];
  __shared__ __align__(16) unsigned short Bs[128 * 32];
  __shared__ __align__(16) unsigned short Al[128 * 128];
  const int tid = threadIdx.x;
  const int w = tid >> 6, lane = tid & 63;
  const int wr = w >> 1, wc = w & 1;
  const int m0 = blockIdx.y * 128;
  const int fr = lane & 15, fq = lane >> 4;
  const int fk = fq << 3;
  const int srow = lane >> 2;
  const int scol = (lane & 3) << 3;

  float rf[4][4];
#pragma unroll
  for (int mi = 0; mi < 4; ++mi)
#pragma unroll
    for (int r = 0; r < 4; ++r)
      rf[mi][r] = rinvF[m0 + wr * 64 + mi * 16 + fq * 4 + r];

  f32x4 acc2[2][2] = {};

  for (int ti = 0; ti < 8; ++ti) {
    const int t = blockIdx.x * 8 + ti;
    if (t >= NT) break;
    const int n0 = t * 128;
    f32x4 acc[4][4] = {};
    for (int kk = 0; kk < D_SZ; kk += 32) {
#pragma unroll
      for (int i = 0; i < 2; ++i) {
        const int chunk = w * 2 + i;
        const int row = chunk * 16 + srow;
        const unsigned short* ga = fn + (size_t)(m0 + row) * D_SZ + kk + scol;
        const unsigned short* gb = exfn + (size_t)(n0 + row) * D_SZ + kk + scol;
        __builtin_amdgcn_global_load_lds((const __attribute__((address_space(1))) void*)ga,
                                         (__attribute__((address_space(3))) void*)&As[chunk * 512],
                                         16, 0, 0);
        __builtin_amdgcn_global_load_lds((const __attribute__((address_space(1))) void*)gb,
                                         (__attribute__((address_space(3))) void*)&Bs[chunk * 512],
                                         16, 0, 0);
      }
      __syncthreads();
      bf16x8 af[4], bfv[4];
#pragma unroll
      for (int i = 0; i < 4; ++i) {
        af[i]  = *(const bf16x8*)&As[(wr * 64 + i * 16 + fr) * 32 + fk];
        bfv[i] = *(const bf16x8*)&Bs[(wc * 64 + i * 16 + fr) * 32 + fk];
      }
#pragma unroll
      for (int mi = 0; mi < 4; ++mi)
#pragma unroll
        for (int ni = 0; ni < 4; ++ni)
          acc[mi][ni] = __builtin_amdgcn_mfma_f32_16x16x32_bf16(af[mi], bfv[ni], acc[mi][ni], 0, 0, 0);
      __syncthreads();
    }
    // scale to cosine, cube, stage a = s^3 into XOR-swizzled LDS tile [b][n]
    float rne[4];
#pragma unroll
    for (int ni = 0; ni < 4; ++ni) rne[ni] = rinvE[n0 + wc * 64 + ni * 16 + fr];
#pragma unroll
    for (int mi = 0; mi < 4; ++mi)
#pragma unroll
      for (int ni = 0; ni < 4; ++ni)
#pragma unroll
        for (int r = 0; r < 4; ++r) {
          const int b = wr * 64 + mi * 16 + fq * 4 + r;
          const int n = wc * 64 + ni * 16 + fr;
          const float s = acc[mi][ni][r] * rf[mi][r] * rne[ni];
          const unsigned byte = (((unsigned)(b * 128 + n)) << 1) ^ ((unsigned)(b & 7) << 4);
          *(unsigned short*)((char*)Al + byte) = f2bf(s * s * s);
        }
    __syncthreads();
    // stage 2: echo_part[b][cls] += a[b][n] * excT[cls][n]; wave w owns rows w*32..+31
#pragma unroll
    for (int kk2 = 0; kk2 < 128; kk2 += 32) {
      bf16x8 pa[2], pb[2];
#pragma unroll
      for (int i = 0; i < 2; ++i) {
        const int b = w * 32 + i * 16 + fr;
        const unsigned byte = (((unsigned)(b * 128 + kk2 + fk)) << 1) ^ ((unsigned)(b & 7) << 4);
        pa[i] = *(const bf16x8*)((const char*)Al + byte);
        const int cls = i * 16 + fr;
        pb[i] = *(const bf16x8*)(excT + (size_t)cls * NP + n0 + kk2 + fk);
      }
#pragma unroll
      for (int mi = 0; mi < 2; ++mi)
#pragma unroll
        for (int ni = 0; ni < 2; ++ni)
          acc2[mi][ni] = __builtin_amdgcn_mfma_f32_16x16x32_bf16(pa[mi], pb[ni], acc2[mi][ni], 0, 0, 0);
    }
    __syncthreads();
  }
#pragma unroll
  for (int mi = 0; mi < 2; ++mi)
#pragma unroll
    for (int ni = 0; ni < 2; ++ni)
#pragma unroll
      for (int r = 0; r < 4; ++r) {
        const int b = w * 32 + mi * 16 + fq * 4 + r;
        const int cls = ni * 16 + fr;
        if (cls < L_SZ)
          atomicAdd(&echo[(size_t)(m0 + b) * L_SZ + cls], acc2[mi][ni][r]);
      }
}

// ---------------------------------------------------------------------------
// Finalize: echo/counts -> neg_dists (vs real class_reps) -> BCE loss.
// ---------------------------------------------------------------------------
__global__ __launch_bounds__(1024)
void finalize(const float* __restrict__ echo, const float* __restrict__ counts,
              const float* __restrict__ labels, const float* __restrict__ creps,
              float* __restrict__ out)
{
  __shared__ float C[L_SZ * L_SZ];
  __shared__ float cnt[L_SZ];
  __shared__ float red[16];
  const int tid = threadIdx.x;
  if (tid < L_SZ * L_SZ) C[tid] = creps[tid];
  if (tid >= 896 && tid < 896 + L_SZ) cnt[tid - 896] = counts[tid - 896];
  __syncthreads();
  float e[L_SZ];
#pragma unroll
  for (int l = 0; l < L_SZ; ++l) e[l] = echo[tid * L_SZ + l] / cnt[l];
  float lsum = 0.f;
  for (int j = 0; j < L_SZ; ++j) {
    float d2 = 0.f;
#pragma unroll
    for (int l = 0; l < L_SZ; ++l) { const float df = e[l] - C[j * L_SZ + l]; d2 += df * df; }
    const float nd = -sqrtf(d2);
    out[1 + tid * L_SZ + j] = nd;
    const float y = labels[tid * L_SZ + j];
    const float sp = fmaxf(nd, 0.f) + log1pf(expf(-fabsf(nd)));
    lsum += sp - nd * y;
  }
#pragma unroll
  for (int o = 32; o; o >>= 1) lsum += __shfl_xor(lsum, o);
  if ((tid & 63) == 0) red[tid >> 6] = lsum;
  __syncthreads();
  if (tid < 16) {
    float v = red[tid];
#pragma unroll
    for (int o = 8; o; o >>= 1) v += __shfl_xor(v, o);
    if (tid == 0) out[0] = v * (1.0f / (B_SZ * L_SZ));
  }
}

extern "C" void kernel_launch(void* const* d_in, const int* in_sizes, int n_in,
                              void* d_out, int out_size, void* d_ws, size_t ws_size,
                              hipStream_t stream)
{
  (void)in_sizes; (void)n_in; (void)out_size;
  const float* features = (const float*)d_in[0];
  const float* labels   = (const float*)d_in[1];
  const float* W_g      = (const float*)d_in[2];
  const float* ex_feat  = (const float*)d_in[3];
  const float* ex_cls   = (const float*)d_in[4];
  const float* creps    = (const float*)d_in[5];
  float* out = (float*)d_out;

  // workspace layout (bytes); excT region aliases Wb (used in disjoint phases)
  const size_t OFF_EXFN = 0;                                       // 76,873,728
  const size_t OFF_FN   = OFF_EXFN + (size_t)NP * D_SZ * 2;        // + 1,572,864
  const size_t OFF_EXCT = OFF_FN + (size_t)B_SZ * D_SZ * 2;        // + 3,203,072 (>= Wb 1,179,648)
  const size_t OFF_ECHO = OFF_EXCT + (size_t)32 * NP * 2;          // + 114,688
  const size_t OFF_CNT  = OFF_ECHO + (size_t)B_SZ * L_SZ * 4;      // + 112
  const size_t OFF_RIE  = OFF_CNT + 112;                           // + NP*4 = 200,192
  const size_t OFF_RIF  = OFF_RIE + (size_t)NP * 4;                // + 4,096
  const size_t NEED = OFF_RIF + (size_t)B_SZ * 4;
  if (ws_size < NEED) return;

  char* ws = (char*)d_ws;
  unsigned short* exfn = (unsigned short*)(ws + OFF_EXFN);
  unsigned short* fnb  = (unsigned short*)(ws + OFF_FN);
  unsigned short* excT = (unsigned short*)(ws + OFF_EXCT);
  unsigned short* Wb   = (unsigned short*)(ws + OFF_EXCT);  // alias, pre-excT phase
  float* echo   = (float*)(ws + OFF_ECHO);
  float* counts = (float*)(ws + OFF_CNT);
  float* rinvE  = (float*)(ws + OFF_RIE);
  float* rinvF  = (float*)(ws + OFF_RIF);

  hipMemsetAsync(echo, 0, (size_t)B_SZ * L_SZ * sizeof(float), stream);

  convW<<<dim3(288), 256, 0, stream>>>(W_g, Wb);
  proj_fused<<<dim3(16 + NP / 64), 512, 0, stream>>>(features, ex_feat, Wb,
                                                     fnb, exfn, rinvF, rinvE);
  excT_prep<<<dim3(NP / 64), 256, 0, stream>>>(ex_cls, excT);   // clobbers Wb (done)
  countsk<<<dim3(L_SZ), 256, 0, stream>>>(ex_cls, counts);
  echo_gemm<<<dim3(49, 8), 256, 0, stream>>>(fnb, exfn, excT, rinvF, rinvE, echo);
  finalize<<<dim3(1), 1024, 0, stream>>>(echo, counts, labels, creps, out);
}

// Round 3
// 429.700 us; speedup vs baseline: 1.4197x; 1.4197x over previous
//
#include <hip/hip_runtime.h>

#define D_SZ 768
#define N_SZ 50000
#define L_SZ 28
#define B_SZ 1024
#define NP   50048   // 391 * 128 (padded N)
#define NT   391     // n-tiles of 128

typedef __bf16 bf16x8 __attribute__((ext_vector_type(8)));
typedef float f32x4 __attribute__((ext_vector_type(4)));
typedef unsigned short u16x8 __attribute__((ext_vector_type(8)));

__device__ __forceinline__ unsigned short f2bf(float f) {
  union { float f; unsigned u; } v; v.f = f;
  unsigned r = v.u + 0x7FFFu + ((v.u >> 16) & 1u);
  return (unsigned short)(r >> 16);
}
__device__ __forceinline__ unsigned cvt_pk_bf16(float lo, float hi) {
  unsigned r;
  asm("v_cvt_pk_bf16_f32 %0, %1, %2" : "=v"(r) : "v"(lo), "v"(hi));
  return r;
}

// ---------------------------------------------------------------------------
// Streaming f32 -> bf16 convert, 8 elems/thread.
// ---------------------------------------------------------------------------
__global__ void conv8(const float* __restrict__ in, unsigned short* __restrict__ out, int n8)
{
  const int t = blockIdx.x * 256 + threadIdx.x;
  if (t >= n8) return;
  const float4 a0 = *(const float4*)(in + (size_t)t * 8);
  const float4 a1 = *(const float4*)(in + (size_t)t * 8 + 4);
  uint4 o;
  o.x = cvt_pk_bf16(a0.x, a0.y);
  o.y = cvt_pk_bf16(a0.z, a0.w);
  o.z = cvt_pk_bf16(a1.x, a1.y);
  o.w = cvt_pk_bf16(a1.z, a1.w);
  *(uint4*)(out + (size_t)t * 8) = o;
}

// ---------------------------------------------------------------------------
// Projection GEMM (round-0 proven structure): Y[M][768] bf16 = X @ W^T.
// 128x128 tile, BK=32, 4 waves 2x2. A staged via global_load_lds when source
// is bf16 (abf), else f32 reg-convert staging (fallback). B (Wb) always bf16
// via global_load_lds. Fused per-row sum-of-squares -> global atomics.
// grid = (6, 399): y<8 -> features, else ex tile (y-8).
// ---------------------------------------------------------------------------
__global__ __launch_bounds__(256, 2)
void proj_gemm2(const unsigned short* __restrict__ Xfb,
                const unsigned short* __restrict__ Xeb,
                const float* __restrict__ Xef,
                const unsigned short* __restrict__ Wb,
                unsigned short* __restrict__ Yf, unsigned short* __restrict__ Ye,
                float* __restrict__ ssqF, float* __restrict__ ssqE,
                int exBf)
{
  __shared__ __align__(16) unsigned short As[128 * 32];
  __shared__ __align__(16) unsigned short Bs[128 * 32];
  const int tid = threadIdx.x;
  const int w = tid >> 6, lane = tid & 63;
  const int wr = w >> 1, wc = w & 1;
  const int fr = lane & 15, fq = lane >> 4;
  const int fk = fq << 3;
  const int srow = lane >> 2;
  const int scol = (lane & 3) << 3;
  const int o0 = blockIdx.x * 128;
  const int y = blockIdx.y;

  const unsigned short* Xb; const float* Xf32; unsigned short* Y;
  float* ssqG; int m0, Mvalid; bool abf;
  if (y < 8) { Xb = Xfb; Xf32 = nullptr; Y = Yf; ssqG = ssqF; m0 = y * 128; Mvalid = B_SZ; abf = true; }
  else { Xb = Xeb; Xf32 = Xef; Y = Ye; ssqG = ssqE; m0 = (y - 8) * 128; Mvalid = N_SZ; abf = (exBf != 0); }

  f32x4 acc[4][4] = {};

  for (int kk = 0; kk < D_SZ; kk += 32) {
    if (abf) {
#pragma unroll
      for (int i = 0; i < 2; ++i) {
        const int chunk = w * 2 + i;
        const int row = chunk * 16 + srow;
        const unsigned short* ga = Xb + (size_t)(m0 + row) * D_SZ + kk + scol;
        __builtin_amdgcn_global_load_lds((const __attribute__((address_space(1))) void*)ga,
                                         (__attribute__((address_space(3))) void*)&As[chunk * 512],
                                         16, 0, 0);
      }
    } else {
#pragma unroll
      for (int i = 0; i < 2; ++i) {
        const int idx = tid + i * 256;
        const int row = idx >> 2;
        const int c8 = (idx & 3) << 3;
        float4 a0, a1;
        if (m0 + row < Mvalid) {
          const float* p = Xf32 + (size_t)(m0 + row) * D_SZ + kk + c8;
          a0 = *(const float4*)p; a1 = *(const float4*)(p + 4);
        } else { a0 = make_float4(0.f, 0.f, 0.f, 0.f); a1 = a0; }
        u16x8 av;
        av[0] = f2bf(a0.x); av[1] = f2bf(a0.y); av[2] = f2bf(a0.z); av[3] = f2bf(a0.w);
        av[4] = f2bf(a1.x); av[5] = f2bf(a1.y); av[6] = f2bf(a1.z); av[7] = f2bf(a1.w);
        *(u16x8*)&As[row * 32 + c8] = av;
      }
    }
#pragma unroll
    for (int i = 0; i < 2; ++i) {
      const int chunk = w * 2 + i;
      const int row = chunk * 16 + srow;
      const unsigned short* gb = Wb + (size_t)(o0 + row) * D_SZ + kk + scol;
      __builtin_amdgcn_global_load_lds((const __attribute__((address_space(1))) void*)gb,
                                       (__attribute__((address_space(3))) void*)&Bs[chunk * 512],
                                       16, 0, 0);
    }
    __syncthreads();
    bf16x8 af[4], bfv[4];
#pragma unroll
    for (int i = 0; i < 4; ++i) {
      af[i]  = *(const bf16x8*)&As[(wr * 64 + i * 16 + fr) * 32 + fk];
      bfv[i] = *(const bf16x8*)&Bs[(wc * 64 + i * 16 + fr) * 32 + fk];
    }
#pragma unroll
    for (int mi = 0; mi < 4; ++mi)
#pragma unroll
      for (int ni = 0; ni < 4; ++ni)
        acc[mi][ni] = __builtin_amdgcn_mfma_f32_16x16x32_bf16(af[mi], bfv[ni], acc[mi][ni], 0, 0, 0);
    __syncthreads();
  }

  float ssq[4][4] = {};
#pragma unroll
  for (int mi = 0; mi < 4; ++mi)
#pragma unroll
    for (int ni = 0; ni < 4; ++ni)
#pragma unroll
      for (int r = 0; r < 4; ++r) {
        const int row = m0 + wr * 64 + mi * 16 + fq * 4 + r;
        const int col = o0 + wc * 64 + ni * 16 + fr;
        const float v = acc[mi][ni][r];
        Y[(size_t)row * D_SZ + col] = f2bf(v);
        ssq[mi][r] += v * v;
      }
#pragma unroll
  for (int mi = 0; mi < 4; ++mi)
#pragma unroll
    for (int r = 0; r < 4; ++r) {
      float v = ssq[mi][r];
      v += __shfl_xor(v, 1); v += __shfl_xor(v, 2);
      v += __shfl_xor(v, 4); v += __shfl_xor(v, 8);
      if (fr == 0) atomicAdd(&ssqG[m0 + wr * 64 + mi * 16 + fq * 4 + r], v);
    }
}

// ---------------------------------------------------------------------------
// Build excT bf16 [32][NP]: excT[l][n] = ex_classes[n][l] (zero-padded).
// ---------------------------------------------------------------------------
__global__ void excT_prep(const float* __restrict__ exc, unsigned short* __restrict__ excT)
{
  __shared__ float lds[64][29];
  const int n0 = blockIdx.x * 64;
  const int tid = threadIdx.x;
  for (int i = tid; i < 64 * L_SZ; i += 256) {
    const int n = i / L_SZ, l = i % L_SZ;
    lds[n][l] = (n0 + n < N_SZ) ? exc[(size_t)(n0 + n) * L_SZ + l] : 0.0f;
  }
  __syncthreads();
  for (int i = tid; i < 32 * 64; i += 256) {
    const int l = i >> 6, n = i & 63;
    const float v = (l < L_SZ) ? lds[n][l] : 0.0f;
    excT[(size_t)l * NP + n0 + n] = f2bf(v);
  }
}

// ---------------------------------------------------------------------------
// Per-class exemplar counts: counts[l] = sum_n ex_classes[n][l].
// ---------------------------------------------------------------------------
__global__ void countsk(const float* __restrict__ exc, float* __restrict__ counts)
{
  const int l = blockIdx.x;
  float c = 0.f;
  for (int n = threadIdx.x; n < N_SZ; n += 256) c += exc[(size_t)n * L_SZ + l];
  __shared__ float red[256];
  red[threadIdx.x] = c;
  __syncthreads();
  for (int s = 128; s; s >>= 1) {
    if (threadIdx.x < s) red[threadIdx.x] += red[threadIdx.x + s];
    __syncthreads();
  }
  if (threadIdx.x == 0) counts[l] = red[0];
}

// ---------------------------------------------------------------------------
// Fused s-GEMM: per 128x128 tile, dot = fn @ exfn^T (K=768, unnormalized),
// s = dot * rinvF[b] * rinvE[n] (rinv from ssq inline), a = s^3 -> swizzled
// LDS, then echo_part += a @ excT^T (K=128) in AGPRs across 8 tiles; atomics.
// ---------------------------------------------------------------------------
__global__ __launch_bounds__(256, 2)
void echo_gemm(const unsigned short* __restrict__ fn,
               const unsigned short* __restrict__ exfn,
               const unsigned short* __restrict__ excT,
               const float* __restrict__ ssqF,
               const float* __restrict__ ssqE,
               float* __restrict__ echo)
{
  __shared__ __align__(16) unsigned short As[128 * 32];
  __shared__ __align__(16) unsigned short Bs[128 * 32];
  __shared__ __align__(16) unsigned short Al[128 * 128];
  const int tid = threadIdx.x;
  const int w = tid >> 6, lane = tid & 63;
  const int wr = w >> 1, wc = w & 1;
  const int m0 = blockIdx.y * 128;
  const int fr = lane & 15, fq = lane >> 4;
  const int fk = fq << 3;
  const int srow = lane >> 2;
  const int scol = (lane & 3) << 3;

  float rf[4][4];
#pragma unroll
  for (int mi = 0; mi < 4; ++mi)
#pragma unroll
    for (int r = 0; r < 4; ++r)
      rf[mi][r] = 1.0f / fmaxf(sqrtf(ssqF[m0 + wr * 64 + mi * 16 + fq * 4 + r]), 1e-12f);

  f32x4 acc2[2][2] = {};

  for (int ti = 0; ti < 8; ++ti) {
    const int t = blockIdx.x * 8 + ti;
    if (t >= NT) break;
    const int n0 = t * 128;
    f32x4 acc[4][4] = {};
    for (int kk = 0; kk < D_SZ; kk += 32) {
#pragma unroll
      for (int i = 0; i < 2; ++i) {
        const int chunk = w * 2 + i;
        const int row = chunk * 16 + srow;
        const unsigned short* ga = fn + (size_t)(m0 + row) * D_SZ + kk + scol;
        const unsigned short* gb = exfn + (size_t)(n0 + row) * D_SZ + kk + scol;
        __builtin_amdgcn_global_load_lds((const __attribute__((address_space(1))) void*)ga,
                                         (__attribute__((address_space(3))) void*)&As[chunk * 512],
                                         16, 0, 0);
        __builtin_amdgcn_global_load_lds((const __attribute__((address_space(1))) void*)gb,
                                         (__attribute__((address_space(3))) void*)&Bs[chunk * 512],
                                         16, 0, 0);
      }
      __syncthreads();
      bf16x8 af[4], bfv[4];
#pragma unroll
      for (int i = 0; i < 4; ++i) {
        af[i]  = *(const bf16x8*)&As[(wr * 64 + i * 16 + fr) * 32 + fk];
        bfv[i] = *(const bf16x8*)&Bs[(wc * 64 + i * 16 + fr) * 32 + fk];
      }
#pragma unroll
      for (int mi = 0; mi < 4; ++mi)
#pragma unroll
        for (int ni = 0; ni < 4; ++ni)
          acc[mi][ni] = __builtin_amdgcn_mfma_f32_16x16x32_bf16(af[mi], bfv[ni], acc[mi][ni], 0, 0, 0);
      __syncthreads();
    }
    // scale to cosine, cube, stage a = s^3 into XOR-swizzled LDS tile [b][n]
    float rne[4];
#pragma unroll
    for (int ni = 0; ni < 4; ++ni)
      rne[ni] = 1.0f / fmaxf(sqrtf(ssqE[n0 + wc * 64 + ni * 16 + fr]), 1e-12f);
#pragma unroll
    for (int mi = 0; mi < 4; ++mi)
#pragma unroll
      for (int ni = 0; ni < 4; ++ni)
#pragma unroll
        for (int r = 0; r < 4; ++r) {
          const int b = wr * 64 + mi * 16 + fq * 4 + r;
          const int n = wc * 64 + ni * 16 + fr;
          const float s = acc[mi][ni][r] * rf[mi][r] * rne[ni];
          const unsigned byte = (((unsigned)(b * 128 + n)) << 1) ^ ((unsigned)(b & 7) << 4);
          *(unsigned short*)((char*)Al + byte) = f2bf(s * s * s);
        }
    __syncthreads();
    // stage 2: echo_part[b][cls] += a[b][n] * excT[cls][n]
#pragma unroll
    for (int kk2 = 0; kk2 < 128; kk2 += 32) {
      bf16x8 pa[2], pb[2];
#pragma unroll
      for (int i = 0; i < 2; ++i) {
        const int b = w * 32 + i * 16 + fr;
        const unsigned byte = (((unsigned)(b * 128 + kk2 + fk)) << 1) ^ ((unsigned)(b & 7) << 4);
        pa[i] = *(const bf16x8*)((const char*)Al + byte);
        const int cls = i * 16 + fr;
        pb[i] = *(const bf16x8*)(excT + (size_t)cls * NP + n0 + kk2 + fk);
      }
#pragma unroll
      for (int mi = 0; mi < 2; ++mi)
#pragma unroll
        for (int ni = 0; ni < 2; ++ni)
          acc2[mi][ni] = __builtin_amdgcn_mfma_f32_16x16x32_bf16(pa[mi], pb[ni], acc2[mi][ni], 0, 0, 0);
    }
    __syncthreads();
  }
#pragma unroll
  for (int mi = 0; mi < 2; ++mi)
#pragma unroll
    for (int ni = 0; ni < 2; ++ni)
#pragma unroll
      for (int r = 0; r < 4; ++r) {
        const int b = w * 32 + mi * 16 + fq * 4 + r;
        const int cls = ni * 16 + fr;
        if (cls < L_SZ)
          atomicAdd(&echo[(size_t)(m0 + b) * L_SZ + cls], acc2[mi][ni][r]);
      }
}

// ---------------------------------------------------------------------------
// Finalize: echo/counts -> neg_dists (vs real class_reps) -> BCE loss.
// ---------------------------------------------------------------------------
__global__ __launch_bounds__(1024)
void finalize(const float* __restrict__ echo, const float* __restrict__ counts,
              const float* __restrict__ labels, const float* __restrict__ creps,
              float* __restrict__ out)
{
  __shared__ float C[L_SZ * L_SZ];
  __shared__ float cnt[L_SZ];
  __shared__ float red[16];
  const int tid = threadIdx.x;
  if (tid < L_SZ * L_SZ) C[tid] = creps[tid];
  if (tid >= 896 && tid < 896 + L_SZ) cnt[tid - 896] = counts[tid - 896];
  __syncthreads();
  float e[L_SZ];
#pragma unroll
  for (int l = 0; l < L_SZ; ++l) e[l] = echo[tid * L_SZ + l] / cnt[l];
  float lsum = 0.f;
  for (int j = 0; j < L_SZ; ++j) {
    float d2 = 0.f;
#pragma unroll
    for (int l = 0; l < L_SZ; ++l) { const float df = e[l] - C[j * L_SZ + l]; d2 += df * df; }
    const float nd = -sqrtf(d2);
    out[1 + tid * L_SZ + j] = nd;
    const float y = labels[tid * L_SZ + j];
    const float sp = fmaxf(nd, 0.f) + log1pf(expf(-fabsf(nd)));
    lsum += sp - nd * y;
  }
#pragma unroll
  for (int o = 32; o; o >>= 1) lsum += __shfl_xor(lsum, o);
  if ((tid & 63) == 0) red[tid >> 6] = lsum;
  __syncthreads();
  if (tid < 16) {
    float v = red[tid];
#pragma unroll
    for (int o = 8; o; o >>= 1) v += __shfl_xor(v, o);
    if (tid == 0) out[0] = v * (1.0f / (B_SZ * L_SZ));
  }
}

extern "C" void kernel_launch(void* const* d_in, const int* in_sizes, int n_in,
                              void* d_out, int out_size, void* d_ws, size_t ws_size,
                              hipStream_t stream)
{
  (void)in_sizes; (void)n_in; (void)out_size;
  const float* features = (const float*)d_in[0];
  const float* labels   = (const float*)d_in[1];
  const float* W_g      = (const float*)d_in[2];
  const float* ex_feat  = (const float*)d_in[3];
  const float* ex_cls   = (const float*)d_in[4];
  const float* creps    = (const float*)d_in[5];
  float* out = (float*)d_out;

  // workspace layout (bytes). Wb and fnXb live inside the excT span
  // (disjoint lifetime: excT_prep runs after proj consumes them).
  const size_t OFF_EXFN = 0;                                       // 76,873,728
  const size_t OFF_FN   = OFF_EXFN + (size_t)NP * D_SZ * 2;        // 76,873,728
  const size_t OFF_EXCT = OFF_FN + (size_t)B_SZ * D_SZ * 2;        // 78,446,592
  const size_t OFF_WB   = OFF_EXCT;                                // 1,179,648 B
  const size_t OFF_FNXB = OFF_EXCT + (size_t)D_SZ * D_SZ * 2;      // 1,572,864 B
  const size_t OFF_ECHO = OFF_EXCT + (size_t)32 * NP * 2;          // 81,649,664
  const size_t OFF_SSQE = OFF_ECHO + (size_t)B_SZ * L_SZ * 4;      // 81,764,352
  const size_t OFF_SSQF = OFF_SSQE + (size_t)NP * 4;               // 81,964,544
  const size_t OFF_CNT  = OFF_SSQF + (size_t)B_SZ * 4;             // 81,968,640
  const size_t NEED_B   = OFF_CNT + 128;                           // 81,968,768
  const size_t OFF_XBE  = NEED_B;
  const size_t NEED_A   = OFF_XBE + (size_t)NP * D_SZ * 2;         // ~158.8 MB
  if (ws_size < NEED_B) return;
  const int useA = (ws_size >= NEED_A) ? 1 : 0;

  char* ws = (char*)d_ws;
  unsigned short* exfn = (unsigned short*)(ws + OFF_EXFN);
  unsigned short* fnb  = (unsigned short*)(ws + OFF_FN);
  unsigned short* excT = (unsigned short*)(ws + OFF_EXCT);
  unsigned short* Wb   = (unsigned short*)(ws + OFF_WB);
  unsigned short* fnXb = (unsigned short*)(ws + OFF_FNXB);
  float* echo   = (float*)(ws + OFF_ECHO);
  float* ssqE   = (float*)(ws + OFF_SSQE);
  float* ssqF   = (float*)(ws + OFF_SSQF);
  float* counts = (float*)(ws + OFF_CNT);
  unsigned short* Xbe = (unsigned short*)(ws + OFF_XBE);

  // zero echo + ssqE + ssqF (contiguous span)
  hipMemsetAsync(ws + OFF_ECHO, 0, OFF_CNT - OFF_ECHO, stream);

  if (useA) {
    // zero the 48 pad rows of Xbe
    hipMemsetAsync((char*)Xbe + (size_t)N_SZ * D_SZ * 2, 0,
                   (size_t)(NP - N_SZ) * D_SZ * 2, stream);
    conv8<<<dim3((N_SZ * D_SZ / 8 + 255) / 256), 256, 0, stream>>>(ex_feat, Xbe, N_SZ * D_SZ / 8);
  }
  conv8<<<dim3((B_SZ * D_SZ / 8 + 255) / 256), 256, 0, stream>>>(features, fnXb, B_SZ * D_SZ / 8);
  conv8<<<dim3((D_SZ * D_SZ / 8 + 255) / 256), 256, 0, stream>>>(W_g, Wb, D_SZ * D_SZ / 8);

  proj_gemm2<<<dim3(6, 8 + NT), 256, 0, stream>>>(fnXb, Xbe, ex_feat, Wb,
                                                  fnb, exfn, ssqF, ssqE, useA);

  excT_prep<<<dim3(NP / 64), 256, 0, stream>>>(ex_cls, excT);   // clobbers Wb/fnXb (done)
  countsk<<<dim3(L_SZ), 256, 0, stream>>>(ex_cls, counts);
  echo_gemm<<<dim3(49, 8), 256, 0, stream>>>(fnb, exfn, excT, ssqF, ssqE, echo);
  finalize<<<dim3(1), 1024, 0, stream>>>(echo, counts, labels, creps, out);
}

// Round 4
// 335.415 us; speedup vs baseline: 1.8188x; 1.2811x over previous
//
#include <hip/hip_runtime.h>

#define D_SZ 768
#define N_SZ 50000
#define L_SZ 28
#define B_SZ 1024
#define NP   50048   // 391 * 128 (padded N)
#define NT   391     // n-tiles of 128

typedef __bf16 bf16x8 __attribute__((ext_vector_type(8)));
typedef float f32x4 __attribute__((ext_vector_type(4)));
typedef unsigned short u16x8 __attribute__((ext_vector_type(8)));

__device__ __forceinline__ unsigned short f2bf(float f) {
  union { float f; unsigned u; } v; v.f = f;
  unsigned r = v.u + 0x7FFFu + ((v.u >> 16) & 1u);
  return (unsigned short)(r >> 16);
}
__device__ __forceinline__ unsigned cvt_pk_bf16(float lo, float hi) {
  unsigned r;
  asm("v_cvt_pk_bf16_f32 %0, %1, %2" : "=v"(r) : "v"(lo), "v"(hi));
  return r;
}

// ---------------------------------------------------------------------------
// Streaming f32 -> bf16 convert, 8 elems/thread.
// ---------------------------------------------------------------------------
__global__ void conv8(const float* __restrict__ in, unsigned short* __restrict__ out, int n8)
{
  const int t = blockIdx.x * 256 + threadIdx.x;
  if (t >= n8) return;
  const float4 a0 = *(const float4*)(in + (size_t)t * 8);
  const float4 a1 = *(const float4*)(in + (size_t)t * 8 + 4);
  uint4 o;
  o.x = cvt_pk_bf16(a0.x, a0.y);
  o.y = cvt_pk_bf16(a0.z, a0.w);
  o.z = cvt_pk_bf16(a1.x, a1.y);
  o.w = cvt_pk_bf16(a1.z, a1.w);
  *(uint4*)(out + (size_t)t * 8) = o;
}

// ---------------------------------------------------------------------------
// Projection GEMM: Y[M][768] bf16 = X @ W^T. 128x128 tile, BK=32, 4 waves.
// Co-XCD id swizzle: the 6 col-blocks sharing one X row-tile land on the same
// XCD (id%8 == y%8) so the X tile is L2-resident after the first fetch.
// id = (y%8) + 8*(x + 6*(y/8)); y<8 -> features, else ex tile (y-8).
// ---------------------------------------------------------------------------
__global__ __launch_bounds__(256, 2)
void proj_gemm2(const unsigned short* __restrict__ Xfb,
                const unsigned short* __restrict__ Xeb,
                const float* __restrict__ Xef,
                const unsigned short* __restrict__ Wb,
                unsigned short* __restrict__ Yf, unsigned short* __restrict__ Ye,
                float* __restrict__ ssqF, float* __restrict__ ssqE,
                int exBf)
{
  const int id = blockIdx.x;
  const int slot = id & 7, rest = id >> 3;
  const int x = rest % 6, yq = rest / 6;
  const int y = yq * 8 + slot;
  if (y >= 8 + NT) return;

  __shared__ __align__(16) unsigned short As[128 * 32];
  __shared__ __align__(16) unsigned short Bs[128 * 32];
  const int tid = threadIdx.x;
  const int w = tid >> 6, lane = tid & 63;
  const int wr = w >> 1, wc = w & 1;
  const int fr = lane & 15, fq = lane >> 4;
  const int fk = fq << 3;
  const int srow = lane >> 2;
  const int scol = (lane & 3) << 3;
  const int o0 = x * 128;

  const unsigned short* Xb; const float* Xf32; unsigned short* Y;
  float* ssqG; int m0, Mvalid; bool abf;
  if (y < 8) { Xb = Xfb; Xf32 = nullptr; Y = Yf; ssqG = ssqF; m0 = y * 128; Mvalid = B_SZ; abf = true; }
  else { Xb = Xeb; Xf32 = Xef; Y = Ye; ssqG = ssqE; m0 = (y - 8) * 128; Mvalid = N_SZ; abf = (exBf != 0); }

  f32x4 acc[4][4] = {};

  for (int kk = 0; kk < D_SZ; kk += 32) {
    if (abf) {
#pragma unroll
      for (int i = 0; i < 2; ++i) {
        const int chunk = w * 2 + i;
        const int row = chunk * 16 + srow;
        const unsigned short* ga = Xb + (size_t)(m0 + row) * D_SZ + kk + scol;
        __builtin_amdgcn_global_load_lds((const __attribute__((address_space(1))) void*)ga,
                                         (__attribute__((address_space(3))) void*)&As[chunk * 512],
                                         16, 0, 0);
      }
    } else {
#pragma unroll
      for (int i = 0; i < 2; ++i) {
        const int idx = tid + i * 256;
        const int row = idx >> 2;
        const int c8 = (idx & 3) << 3;
        float4 a0, a1;
        if (m0 + row < Mvalid) {
          const float* p = Xf32 + (size_t)(m0 + row) * D_SZ + kk + c8;
          a0 = *(const float4*)p; a1 = *(const float4*)(p + 4);
        } else { a0 = make_float4(0.f, 0.f, 0.f, 0.f); a1 = a0; }
        u16x8 av;
        av[0] = f2bf(a0.x); av[1] = f2bf(a0.y); av[2] = f2bf(a0.z); av[3] = f2bf(a0.w);
        av[4] = f2bf(a1.x); av[5] = f2bf(a1.y); av[6] = f2bf(a1.z); av[7] = f2bf(a1.w);
        *(u16x8*)&As[row * 32 + c8] = av;
      }
    }
#pragma unroll
    for (int i = 0; i < 2; ++i) {
      const int chunk = w * 2 + i;
      const int row = chunk * 16 + srow;
      const unsigned short* gb = Wb + (size_t)(o0 + row) * D_SZ + kk + scol;
      __builtin_amdgcn_global_load_lds((const __attribute__((address_space(1))) void*)gb,
                                       (__attribute__((address_space(3))) void*)&Bs[chunk * 512],
                                       16, 0, 0);
    }
    __syncthreads();
    bf16x8 af[4], bfv[4];
#pragma unroll
    for (int i = 0; i < 4; ++i) {
      af[i]  = *(const bf16x8*)&As[(wr * 64 + i * 16 + fr) * 32 + fk];
      bfv[i] = *(const bf16x8*)&Bs[(wc * 64 + i * 16 + fr) * 32 + fk];
    }
#pragma unroll
    for (int mi = 0; mi < 4; ++mi)
#pragma unroll
      for (int ni = 0; ni < 4; ++ni)
        acc[mi][ni] = __builtin_amdgcn_mfma_f32_16x16x32_bf16(af[mi], bfv[ni], acc[mi][ni], 0, 0, 0);
    __syncthreads();
  }

  float ssq[4][4] = {};
#pragma unroll
  for (int mi = 0; mi < 4; ++mi)
#pragma unroll
    for (int ni = 0; ni < 4; ++ni)
#pragma unroll
      for (int r = 0; r < 4; ++r) {
        const int row = m0 + wr * 64 + mi * 16 + fq * 4 + r;
        const int col = o0 + wc * 64 + ni * 16 + fr;
        const float v = acc[mi][ni][r];
        Y[(size_t)row * D_SZ + col] = f2bf(v);
        ssq[mi][r] += v * v;
      }
#pragma unroll
  for (int mi = 0; mi < 4; ++mi)
#pragma unroll
    for (int r = 0; r < 4; ++r) {
      float v = ssq[mi][r];
      v += __shfl_xor(v, 1); v += __shfl_xor(v, 2);
      v += __shfl_xor(v, 4); v += __shfl_xor(v, 8);
      if (fr == 0) atomicAdd(&ssqG[m0 + wr * 64 + mi * 16 + fq * 4 + r], v);
    }
}

// ---------------------------------------------------------------------------
// Build excT bf16 [32][NP] + fused per-class counts.
// ---------------------------------------------------------------------------
__global__ void excT_prep(const float* __restrict__ exc, unsigned short* __restrict__ excT,
                          float* __restrict__ counts)
{
  __shared__ float lds[64][29];
  const int n0 = blockIdx.x * 64;
  const int tid = threadIdx.x;
  for (int i = tid; i < 64 * L_SZ; i += 256) {
    const int n = i / L_SZ, l = i % L_SZ;
    lds[n][l] = (n0 + n < N_SZ) ? exc[(size_t)(n0 + n) * L_SZ + l] : 0.0f;
  }
  __syncthreads();
  if (tid < L_SZ) {
    float c = 0.f;
    for (int n = 0; n < 64; ++n) c += lds[n][tid];
    atomicAdd(&counts[tid], c);
  }
  for (int i = tid; i < 32 * 64; i += 256) {
    const int l = i >> 6, n = i & 63;
    const float v = (l < L_SZ) ? lds[n][l] : 0.0f;
    excT[(size_t)l * NP + n0 + n] = f2bf(v);
  }
}

// ---------------------------------------------------------------------------
// Fused s-GEMM. Co-XCD id swizzle: the 8 m-blocks consuming the same exfn
// 8-tile slab land on one XCD (id%8 == x%8) -> slab fetched into that XCD's
// L2 once, hit 7x. id = (x%8) + 8*(m + 8*(x/8)), x in [0,49).
// ---------------------------------------------------------------------------
__global__ __launch_bounds__(256, 2)
void echo_gemm(const unsigned short* __restrict__ fn,
               const unsigned short* __restrict__ exfn,
               const unsigned short* __restrict__ excT,
               const float* __restrict__ ssqF,
               const float* __restrict__ ssqE,
               float* __restrict__ echo)
{
  const int id = blockIdx.x;
  const int slot = id & 7, rest = id >> 3;
  const int m = rest & 7, xq = rest >> 3;
  const int x = xq * 8 + slot;
  if (x >= 49) return;
  const int m0 = m * 128;

  __shared__ __align__(16) unsigned short As[128 * 32];
  __shared__ __align__(16) unsigned short Bs[128 * 32];
  __shared__ __align__(16) unsigned short Al[128 * 128];
  const int tid = threadIdx.x;
  const int w = tid >> 6, lane = tid & 63;
  const int wr = w >> 1, wc = w & 1;
  const int fr = lane & 15, fq = lane >> 4;
  const int fk = fq << 3;
  const int srow = lane >> 2;
  const int scol = (lane & 3) << 3;

  float rf[4][4];
#pragma unroll
  for (int mi = 0; mi < 4; ++mi)
#pragma unroll
    for (int r = 0; r < 4; ++r)
      rf[mi][r] = 1.0f / fmaxf(sqrtf(ssqF[m0 + wr * 64 + mi * 16 + fq * 4 + r]), 1e-12f);

  f32x4 acc2[2][2] = {};

  for (int ti = 0; ti < 8; ++ti) {
    const int t = x * 8 + ti;
    if (t >= NT) break;
    const int n0 = t * 128;
    f32x4 acc[4][4] = {};
    for (int kk = 0; kk < D_SZ; kk += 32) {
#pragma unroll
      for (int i = 0; i < 2; ++i) {
        const int chunk = w * 2 + i;
        const int row = chunk * 16 + srow;
        const unsigned short* ga = fn + (size_t)(m0 + row) * D_SZ + kk + scol;
        const unsigned short* gb = exfn + (size_t)(n0 + row) * D_SZ + kk + scol;
        __builtin_amdgcn_global_load_lds((const __attribute__((address_space(1))) void*)ga,
                                         (__attribute__((address_space(3))) void*)&As[chunk * 512],
                                         16, 0, 0);
        __builtin_amdgcn_global_load_lds((const __attribute__((address_space(1))) void*)gb,
                                         (__attribute__((address_space(3))) void*)&Bs[chunk * 512],
                                         16, 0, 0);
      }
      __syncthreads();
      bf16x8 af[4], bfv[4];
#pragma unroll
      for (int i = 0; i < 4; ++i) {
        af[i]  = *(const bf16x8*)&As[(wr * 64 + i * 16 + fr) * 32 + fk];
        bfv[i] = *(const bf16x8*)&Bs[(wc * 64 + i * 16 + fr) * 32 + fk];
      }
#pragma unroll
      for (int mi = 0; mi < 4; ++mi)
#pragma unroll
        for (int ni = 0; ni < 4; ++ni)
          acc[mi][ni] = __builtin_amdgcn_mfma_f32_16x16x32_bf16(af[mi], bfv[ni], acc[mi][ni], 0, 0, 0);
      __syncthreads();
    }
    // scale to cosine, cube, stage a = s^3 into XOR-swizzled LDS tile [b][n]
    float rne[4];
#pragma unroll
    for (int ni = 0; ni < 4; ++ni)
      rne[ni] = 1.0f / fmaxf(sqrtf(ssqE[n0 + wc * 64 + ni * 16 + fr]), 1e-12f);
#pragma unroll
    for (int mi = 0; mi < 4; ++mi)
#pragma unroll
      for (int ni = 0; ni < 4; ++ni)
#pragma unroll
        for (int r = 0; r < 4; ++r) {
          const int b = wr * 64 + mi * 16 + fq * 4 + r;
          const int n = wc * 64 + ni * 16 + fr;
          const float s = acc[mi][ni][r] * rf[mi][r] * rne[ni];
          const unsigned byte = (((unsigned)(b * 128 + n)) << 1) ^ ((unsigned)(b & 7) << 4);
          *(unsigned short*)((char*)Al + byte) = f2bf(s * s * s);
        }
    __syncthreads();
    // stage 2: echo_part[b][cls] += a[b][n] * excT[cls][n]
#pragma unroll
    for (int kk2 = 0; kk2 < 128; kk2 += 32) {
      bf16x8 pa[2], pb[2];
#pragma unroll
      for (int i = 0; i < 2; ++i) {
        const int b = w * 32 + i * 16 + fr;
        const unsigned byte = (((unsigned)(b * 128 + kk2 + fk)) << 1) ^ ((unsigned)(b & 7) << 4);
        pa[i] = *(const bf16x8*)((const char*)Al + byte);
        const int cls = i * 16 + fr;
        pb[i] = *(const bf16x8*)(excT + (size_t)cls * NP + n0 + kk2 + fk);
      }
#pragma unroll
      for (int mi = 0; mi < 2; ++mi)
#pragma unroll
        for (int ni = 0; ni < 2; ++ni)
          acc2[mi][ni] = __builtin_amdgcn_mfma_f32_16x16x32_bf16(pa[mi], pb[ni], acc2[mi][ni], 0, 0, 0);
    }
    __syncthreads();
  }
#pragma unroll
  for (int mi = 0; mi < 2; ++mi)
#pragma unroll
    for (int ni = 0; ni < 2; ++ni)
#pragma unroll
      for (int r = 0; r < 4; ++r) {
        const int b = w * 32 + mi * 16 + fq * 4 + r;
        const int cls = ni * 16 + fr;
        if (cls < L_SZ)
          atomicAdd(&echo[(size_t)(m0 + b) * L_SZ + cls], acc2[mi][ni][r]);
      }
}

// ---------------------------------------------------------------------------
// Finalize: echo/counts -> neg_dists (vs real class_reps) -> BCE loss.
// ---------------------------------------------------------------------------
__global__ __launch_bounds__(1024)
void finalize(const float* __restrict__ echo, const float* __restrict__ counts,
              const float* __restrict__ labels, const float* __restrict__ creps,
              float* __restrict__ out)
{
  __shared__ float C[L_SZ * L_SZ];
  __shared__ float cnt[L_SZ];
  __shared__ float red[16];
  const int tid = threadIdx.x;
  if (tid < L_SZ * L_SZ) C[tid] = creps[tid];
  if (tid >= 896 && tid < 896 + L_SZ) cnt[tid - 896] = counts[tid - 896];
  __syncthreads();
  float e[L_SZ];
#pragma unroll
  for (int l = 0; l < L_SZ; ++l) e[l] = echo[tid * L_SZ + l] / cnt[l];
  float lsum = 0.f;
  for (int j = 0; j < L_SZ; ++j) {
    float d2 = 0.f;
#pragma unroll
    for (int l = 0; l < L_SZ; ++l) { const float df = e[l] - C[j * L_SZ + l]; d2 += df * df; }
    const float nd = -sqrtf(d2);
    out[1 + tid * L_SZ + j] = nd;
    const float y = labels[tid * L_SZ + j];
    const float sp = fmaxf(nd, 0.f) + log1pf(expf(-fabsf(nd)));
    lsum += sp - nd * y;
  }
#pragma unroll
  for (int o = 32; o; o >>= 1) lsum += __shfl_xor(lsum, o);
  if ((tid & 63) == 0) red[tid >> 6] = lsum;
  __syncthreads();
  if (tid < 16) {
    float v = red[tid];
#pragma unroll
    for (int o = 8; o; o >>= 1) v += __shfl_xor(v, o);
    if (tid == 0) out[0] = v * (1.0f / (B_SZ * L_SZ));
  }
}

extern "C" void kernel_launch(void* const* d_in, const int* in_sizes, int n_in,
                              void* d_out, int out_size, void* d_ws, size_t ws_size,
                              hipStream_t stream)
{
  (void)in_sizes; (void)n_in; (void)out_size;
  const float* features = (const float*)d_in[0];
  const float* labels   = (const float*)d_in[1];
  const float* W_g      = (const float*)d_in[2];
  const float* ex_feat  = (const float*)d_in[3];
  const float* ex_cls   = (const float*)d_in[4];
  const float* creps    = (const float*)d_in[5];
  float* out = (float*)d_out;

  const size_t OFF_EXFN = 0;
  const size_t OFF_FN   = OFF_EXFN + (size_t)NP * D_SZ * 2;
  const size_t OFF_EXCT = OFF_FN + (size_t)B_SZ * D_SZ * 2;
  const size_t OFF_WB   = OFF_EXCT;                                // alias (disjoint lifetime)
  const size_t OFF_FNXB = OFF_EXCT + (size_t)D_SZ * D_SZ * 2;
  const size_t OFF_ECHO = OFF_EXCT + (size_t)32 * NP * 2;
  const size_t OFF_SSQE = OFF_ECHO + (size_t)B_SZ * L_SZ * 4;
  const size_t OFF_SSQF = OFF_SSQE + (size_t)NP * 4;
  const size_t OFF_CNT  = OFF_SSQF + (size_t)B_SZ * 4;
  const size_t NEED_B   = OFF_CNT + 128;
  const size_t OFF_XBE  = NEED_B;
  const size_t NEED_A   = OFF_XBE + (size_t)NP * D_SZ * 2;
  if (ws_size < NEED_B) return;
  const int useA = (ws_size >= NEED_A) ? 1 : 0;

  char* ws = (char*)d_ws;
  unsigned short* exfn = (unsigned short*)(ws + OFF_EXFN);
  unsigned short* fnb  = (unsigned short*)(ws + OFF_FN);
  unsigned short* excT = (unsigned short*)(ws + OFF_EXCT);
  unsigned short* Wb   = (unsigned short*)(ws + OFF_WB);
  unsigned short* fnXb = (unsigned short*)(ws + OFF_FNXB);
  float* echo   = (float*)(ws + OFF_ECHO);
  float* ssqE   = (float*)(ws + OFF_SSQE);
  float* ssqF   = (float*)(ws + OFF_SSQF);
  float* counts = (float*)(ws + OFF_CNT);
  unsigned short* Xbe = (unsigned short*)(ws + OFF_XBE);

  // zero echo + ssqE + ssqF + counts (contiguous span)
  hipMemsetAsync(ws + OFF_ECHO, 0, OFF_CNT + 128 - OFF_ECHO, stream);

  if (useA) {
    hipMemsetAsync((char*)Xbe + (size_t)N_SZ * D_SZ * 2, 0,
                   (size_t)(NP - N_SZ) * D_SZ * 2, stream);
    conv8<<<dim3((N_SZ * D_SZ / 8 + 255) / 256), 256, 0, stream>>>(ex_feat, Xbe, N_SZ * D_SZ / 8);
  }
  conv8<<<dim3((B_SZ * D_SZ / 8 + 255) / 256), 256, 0, stream>>>(features, fnXb, B_SZ * D_SZ / 8);
  conv8<<<dim3((D_SZ * D_SZ / 8 + 255) / 256), 256, 0, stream>>>(W_g, Wb, D_SZ * D_SZ / 8);

  // grid: id = (y%8) + 8*(x + 6*(y/8)), y in [0,399), x in [0,6)
  proj_gemm2<<<dim3(8 * 6 * 50), 256, 0, stream>>>(fnXb, Xbe, ex_feat, Wb,
                                                   fnb, exfn, ssqF, ssqE, useA);

  excT_prep<<<dim3(NP / 64), 256, 0, stream>>>(ex_cls, excT, counts);  // clobbers Wb/fnXb (done)
  // grid: id = (x%8) + 8*(m + 8*(x/8)), x in [0,49), m in [0,8)
  echo_gemm<<<dim3(8 * 8 * 7), 256, 0, stream>>>(fnb, exfn, excT, ssqF, ssqE, echo);
  finalize<<<dim3(1), 1024, 0, stream>>>(echo, counts, labels, creps, out);
}